// Round 2
// baseline (1475.092 us; speedup 1.0000x reference)
//
#include <hip/hip_runtime.h>
#include <math.h>

#define B_  2048
#define T_  200
#define D_  64
#define H1_ 80
#define H2_ 40

// One workgroup (256 threads) per batch element b.
// Algebra: info@W1 = q@(W1a+W1c) + k@(W1b - W1c + diag(q)W1d)
//   base1[j] = b1[j] + sum_i q_i (W1[i][j] + W1[128+i][j])         (per b)
//   Wq[i][j] = W1[64+i][j] - W1[128+i][j] + q_i * W1[192+i][j]     (per b, LDS)
//   h1_pre[t][j] = base1[j] + sum_i k[t][i] * Wq[i][j]             (per t, K=64)
//
// R2: no barriers inside the per-t MLP (k read straight from global into
// registers) so h1[80]/h2[40] stay in VGPRs — R1 spilled ~940 MB of scratch
// because the arrays were live across the k-chunk __syncthreads().
__global__ __launch_bounds__(256, 2)
void att_kernel(const float* __restrict__ q,
                const float* __restrict__ k,
                const float* __restrict__ v,
                const float* __restrict__ W1,
                const float* __restrict__ b1,
                const float* __restrict__ a1,
                const float* __restrict__ W2,
                const float* __restrict__ b2,
                const float* __restrict__ a2,
                const float* __restrict__ Wf,
                const float* __restrict__ bf,
                float* __restrict__ out)
{
    const int b   = blockIdx.x;
    const int tid = threadIdx.x;

    __shared__ float lds_q[64];
    __shared__ float lds_wq[64 * 80];      // 20 KB, broadcast reads (b128-aligned rows)
    __shared__ float lds_w2[80 * 40];      // 12.8 KB, broadcast reads
    __shared__ float lds_base1[80];
    __shared__ float lds_wf[40];
    __shared__ float lds_red[256];
    __shared__ float lds_w[256];
    __shared__ float lds_acc[256];

    const float* kb = k + (size_t)b * T_ * D_;
    const float* vb = v + (size_t)b * T_ * D_;

    // ---- phase 0: small loads
    if (tid < 64) lds_q[tid] = q[b * 64 + tid];
    if (tid < 40) lds_wf[tid] = Wf[tid];
    __syncthreads();

    // ---- phase 1: build per-b Wq, base1; stage W2
    for (int idx = tid; idx < 64 * 80; idx += 256) {
        int i = idx / 80, j = idx - i * 80;
        lds_wq[idx] = W1[(64 + i) * 80 + j] - W1[(128 + i) * 80 + j]
                    + lds_q[i] * W1[(192 + i) * 80 + j];
    }
    if (tid < 80) {
        float s = b1[tid];
        #pragma unroll 8
        for (int i = 0; i < 64; ++i)
            s += lds_q[i] * (W1[i * 80 + tid] + W1[(128 + i) * 80 + tid]);
        lds_base1[tid] = s;
    }
    for (int idx = tid; idx < 80 * 40; idx += 256) lds_w2[idx] = W2[idx];
    __syncthreads();

    // ---- phase 2: per-t MLP, zero barriers, all state in VGPRs
    const int t = tid;
    float logit = -INFINITY;
    if (t < T_) {
        float h1[H1_];
        {
            const float4* b14 = (const float4*)lds_base1;
            #pragma unroll
            for (int j4 = 0; j4 < 20; ++j4) {
                float4 s = b14[j4];
                h1[j4 * 4 + 0] = s.x; h1[j4 * 4 + 1] = s.y;
                h1[j4 * 4 + 2] = s.z; h1[j4 * 4 + 3] = s.w;
            }
        }
        const float4* krow4 = (const float4*)(kb + t * D_);
        #pragma unroll 4
        for (int i4 = 0; i4 < 16; ++i4) {
            const float4 kv4 = krow4[i4];
            #pragma unroll
            for (int c = 0; c < 4; ++c) {
                const float kv = (c == 0) ? kv4.x : (c == 1) ? kv4.y
                               : (c == 2) ? kv4.z : kv4.w;
                const float4* wq4 = (const float4*)&lds_wq[(i4 * 4 + c) * H1_];
                #pragma unroll
                for (int j4 = 0; j4 < 20; ++j4) {
                    float4 w = wq4[j4];
                    h1[j4 * 4 + 0] += kv * w.x;
                    h1[j4 * 4 + 1] += kv * w.y;
                    h1[j4 * 4 + 2] += kv * w.z;
                    h1[j4 * 4 + 3] += kv * w.w;
                }
            }
        }
        // PReLU 1 (alpha depends on t)
        const float4* a1p = (const float4*)(a1 + t * H1_);
        #pragma unroll
        for (int j4 = 0; j4 < 20; ++j4) {
            float4 a = a1p[j4];
            float x;
            x = h1[j4 * 4 + 0]; h1[j4 * 4 + 0] = x > 0.f ? x : a.x * x;
            x = h1[j4 * 4 + 1]; h1[j4 * 4 + 1] = x > 0.f ? x : a.y * x;
            x = h1[j4 * 4 + 2]; h1[j4 * 4 + 2] = x > 0.f ? x : a.z * x;
            x = h1[j4 * 4 + 3]; h1[j4 * 4 + 3] = x > 0.f ? x : a.w * x;
        }
        // Dense 2
        float h2[H2_];
        {
            const float* b2p = b2;   // uniform -> scalar loads
            #pragma unroll
            for (int jj = 0; jj < H2_; ++jj) h2[jj] = b2p[jj];
        }
        #pragma unroll 4
        for (int j = 0; j < H1_; ++j) {
            const float hv = h1[j];
            const float4* w2r = (const float4*)&lds_w2[j * H2_];
            #pragma unroll
            for (int q4 = 0; q4 < 10; ++q4) {
                float4 w = w2r[q4];
                h2[q4 * 4 + 0] += hv * w.x;
                h2[q4 * 4 + 1] += hv * w.y;
                h2[q4 * 4 + 2] += hv * w.z;
                h2[q4 * 4 + 3] += hv * w.w;
            }
        }
        // PReLU 2 + final dot
        const float4* a2p = (const float4*)(a2 + t * H2_);
        const float4* wf4p = (const float4*)lds_wf;
        float s = bf[0];
        #pragma unroll
        for (int q4 = 0; q4 < 10; ++q4) {
            float4 a  = a2p[q4];
            float4 wf = wf4p[q4];
            float x;
            x = h2[q4 * 4 + 0]; x = x > 0.f ? x : a.x * x; s += x * wf.x;
            x = h2[q4 * 4 + 1]; x = x > 0.f ? x : a.y * x; s += x * wf.y;
            x = h2[q4 * 4 + 2]; x = x > 0.f ? x : a.z * x; s += x * wf.z;
            x = h2[q4 * 4 + 3]; x = x > 0.f ? x : a.w * x; s += x * wf.w;
        }
        logit = s;
    }

    // ---- softmax over t (block-wide)
    lds_red[tid] = logit;
    __syncthreads();
    for (int off = 128; off > 0; off >>= 1) {
        if (tid < off) lds_red[tid] = fmaxf(lds_red[tid], lds_red[tid + off]);
        __syncthreads();
    }
    const float mx = lds_red[0];
    __syncthreads();
    const float ew = (t < T_) ? __expf(logit - mx) : 0.0f;
    lds_red[tid] = ew;
    __syncthreads();
    for (int off = 128; off > 0; off >>= 1) {
        if (tid < off) lds_red[tid] += lds_red[tid + off];
        __syncthreads();
    }
    const float inv = 1.0f / lds_red[0];
    lds_w[tid] = ew * inv;
    __syncthreads();

    // ---- out[b][d] = sum_t w_t * v[b][t][d]
    const int g = tid >> 6, d = tid & 63;
    float acc = 0.0f;
    for (int tt = g; tt < T_; tt += 4)
        acc += lds_w[tt] * vb[tt * 64 + d];
    lds_acc[tid] = acc;
    __syncthreads();
    if (tid < 64)
        out[b * 64 + tid] = lds_acc[tid] + lds_acc[64 + tid]
                          + lds_acc[128 + tid] + lds_acc[192 + tid];
}

extern "C" void kernel_launch(void* const* d_in, const int* in_sizes, int n_in,
                              void* d_out, int out_size, void* d_ws, size_t ws_size,
                              hipStream_t stream) {
    const float* q  = (const float*)d_in[0];
    const float* k  = (const float*)d_in[1];
    const float* v  = (const float*)d_in[2];
    const float* W1 = (const float*)d_in[3];
    const float* b1 = (const float*)d_in[4];
    const float* a1 = (const float*)d_in[5];
    const float* W2 = (const float*)d_in[6];
    const float* b2 = (const float*)d_in[7];
    const float* a2 = (const float*)d_in[8];
    const float* Wf = (const float*)d_in[9];
    const float* bf = (const float*)d_in[10];
    float* out = (float*)d_out;

    hipLaunchKernelGGL(att_kernel, dim3(B_), dim3(256), 0, stream,
                       q, k, v, W1, b1, a1, W2, b2, a2, Wf, bf, out);
}

// Round 3
// 458.138 us; speedup vs baseline: 3.2198x; 3.2198x over previous
//
#include <hip/hip_runtime.h>
#include <math.h>

#define B_  2048
#define T_  200
#define D_  64
#define H1_ 80
#define H2_ 40

// One block per batch element. Register-tiled GEMM, ALL accumulators
// constant-indexed (R1/R2 post-mortem: dynamic indexing of private arrays
// forced them to scratch -> 0.7-3.4 GB of spill traffic).
//
// Algebra: info@W1 = q@(W1a+W1c) + k@(W1b - W1c + diag(q)W1d)
//   base1[j] = b1[j] + sum_i q_i (W1[i][j] + W1[128+i][j])      (per b)
//   Wq[i][j] = W1[64+i][j] - W1[128+i][j] + q_i * W1[192+i][j]  (per b, LDS)
//   h1pre[t][j] = base1[j] + sum_i k[t][i] * Wq[i][j]           (K=64)
//
// Thread mapping (per pass of 100 rows): colg = tid&3 (20 h1-cols / 10
// h2-cols), rowg = tid>>2 (2 rows, active rowg<50). k and h1 stored
// TRANSPOSED in LDS (stride 104) so row-pairs come from one ds_read_b64;
// weight reads are wave-broadcast b128 (disjoint bank quads).
__global__ __launch_bounds__(256, 2)
void att_kernel(const float* __restrict__ q,
                const float* __restrict__ k,
                const float* __restrict__ v,
                const float* __restrict__ W1,
                const float* __restrict__ b1,
                const float* __restrict__ a1,
                const float* __restrict__ W2,
                const float* __restrict__ b2,
                const float* __restrict__ a2,
                const float* __restrict__ Wf,
                const float* __restrict__ bf,
                float* __restrict__ out)
{
    const int b    = blockIdx.x;
    const int tid  = threadIdx.x;
    const int colg = tid & 3;
    const int rowg = tid >> 2;

    __shared__ float bufU[80 * 104];      // kT[64][104] then h1T[80][104] (33.3 KB)
    __shared__ float lds_wq[64 * 80];     // 20 KB
    __shared__ float lds_w2p[4 * 964];    // [colg][j][12-pad] + 4-float skew (15.4 KB)
    __shared__ float lds_q[64];
    __shared__ float lds_base1[80];
    __shared__ float lds_b2[40];
    __shared__ float lds_wf[40];
    __shared__ float lds_part[4 * 128];
    __shared__ float lds_logits[256];
    __shared__ float lds_red[256];
    __shared__ float lds_w[256];
    __shared__ float lds_acc[256];
    __shared__ float lds_bf;

    const float* kb = k + (size_t)b * T_ * D_;
    const float* vb = v + (size_t)b * T_ * D_;

    // ---- phase 0: tiny loads
    if (tid < 64) lds_q[tid] = q[b * 64 + tid];
    if (tid < 40) { lds_b2[tid] = b2[tid]; lds_wf[tid] = Wf[tid]; }
    if (tid == 0) lds_bf = bf[0];
    __syncthreads();

    // ---- phase 1: per-b weights
    for (int idx = tid; idx < 5120; idx += 256) {   // Wq (coalesced W1 reads)
        lds_wq[idx] = W1[5120 + idx] - W1[10240 + idx]
                    + lds_q[idx / 80] * W1[15360 + idx];
    }
    if (tid < 80) {                                  // base1
        float s = b1[tid];
        #pragma unroll 4
        for (int i = 0; i < 64; ++i)
            s += lds_q[i] * (W1[i * 80 + tid] + W1[10240 + i * 80 + tid]);
        lds_base1[tid] = s;
    }
    for (int idx = tid; idx < 3200; idx += 256) {    // W2 -> padded per-colg layout
        int u = idx % 10; int jj = (idx / 10) % 80; int c = idx / 800;
        lds_w2p[c * 964 + jj * 12 + u] = W2[jj * 40 + c * 10 + u];
    }

    for (int pass = 0; pass < 2; ++pass) {
        __syncthreads();  // (a) weights ready / previous pass fully consumed

        // ---- stage k rows [pass*100, pass*100+100) transposed into bufU
        {
            const float4* ksrc = (const float4*)(kb + pass * 100 * 64);
            for (int idx = tid; idx < 1600; idx += 256) {
                const int lr = idx >> 4, c4 = idx & 15;
                const float4 kv = ksrc[idx];           // coalesced
                bufU[(c4 * 4 + 0) * 104 + lr] = kv.x;
                bufU[(c4 * 4 + 1) * 104 + lr] = kv.y;
                bufU[(c4 * 4 + 2) * 104 + lr] = kv.z;
                bufU[(c4 * 4 + 3) * 104 + lr] = kv.w;
            }
        }
        __syncthreads();  // (b)

        // ---- Dense1: acc[2 rows][20 cols], constant-indexed
        float4 acc[2][5];
        {
            const float4* bs = (const float4*)(lds_base1 + colg * 20);
            #pragma unroll
            for (int u4 = 0; u4 < 5; ++u4) { acc[0][u4] = bs[u4]; acc[1][u4] = bs[u4]; }
        }
        if (rowg < 50) {
            #pragma unroll 2
            for (int kk = 0; kk < 64; ++kk) {
                const float2 kv = *(const float2*)&bufU[kk * 104 + rowg * 2];
                const float4* wq4 = (const float4*)&lds_wq[kk * 80 + colg * 20];
                #pragma unroll
                for (int u4 = 0; u4 < 5; ++u4) {
                    const float4 w = wq4[u4];
                    acc[0][u4].x += kv.x * w.x; acc[0][u4].y += kv.x * w.y;
                    acc[0][u4].z += kv.x * w.z; acc[0][u4].w += kv.x * w.w;
                    acc[1][u4].x += kv.y * w.x; acc[1][u4].y += kv.y * w.y;
                    acc[1][u4].z += kv.y * w.z; acc[1][u4].w += kv.y * w.w;
                }
            }
        }
        __syncthreads();  // (c) kT fully consumed; bufU may be rewritten

        // ---- PReLU1 + store h1 transposed
        if (rowg < 50) {
            #pragma unroll
            for (int rr = 0; rr < 2; ++rr) {
                const int lr = rowg * 2 + rr;
                const int t  = pass * 100 + lr;
                const float4* a1p = (const float4*)(a1 + t * 80 + colg * 20);
                #pragma unroll
                for (int u4 = 0; u4 < 5; ++u4) {
                    const float4 a = a1p[u4];
                    const float4 x = acc[rr][u4];
                    const int j0 = colg * 20 + u4 * 4;
                    bufU[(j0 + 0) * 104 + lr] = x.x > 0.f ? x.x : a.x * x.x;
                    bufU[(j0 + 1) * 104 + lr] = x.y > 0.f ? x.y : a.y * x.y;
                    bufU[(j0 + 2) * 104 + lr] = x.z > 0.f ? x.z : a.z * x.z;
                    bufU[(j0 + 3) * 104 + lr] = x.w > 0.f ? x.w : a.w * x.w;
                }
            }
        }
        __syncthreads();  // (d)

        // ---- Dense2: h2[2 rows][10 cols], constant-indexed
        float h2a[2][10];
        #pragma unroll
        for (int u = 0; u < 10; ++u) {
            h2a[0][u] = lds_b2[colg * 10 + u];
            h2a[1][u] = h2a[0][u];
        }
        if (rowg < 50) {
            #pragma unroll 2
            for (int j = 0; j < 80; ++j) {
                const float2 hv = *(const float2*)&bufU[j * 104 + rowg * 2];
                const float* wr = &lds_w2p[colg * 964 + j * 12];
                const float4 wa = *(const float4*)(wr);
                const float4 wb = *(const float4*)(wr + 4);
                const float2 wc = *(const float2*)(wr + 8);
                h2a[0][0] += hv.x * wa.x; h2a[0][1] += hv.x * wa.y;
                h2a[0][2] += hv.x * wa.z; h2a[0][3] += hv.x * wa.w;
                h2a[0][4] += hv.x * wb.x; h2a[0][5] += hv.x * wb.y;
                h2a[0][6] += hv.x * wb.z; h2a[0][7] += hv.x * wb.w;
                h2a[0][8] += hv.x * wc.x; h2a[0][9] += hv.x * wc.y;
                h2a[1][0] += hv.y * wa.x; h2a[1][1] += hv.y * wa.y;
                h2a[1][2] += hv.y * wa.z; h2a[1][3] += hv.y * wa.w;
                h2a[1][4] += hv.y * wb.x; h2a[1][5] += hv.y * wb.y;
                h2a[1][6] += hv.y * wb.z; h2a[1][7] += hv.y * wb.w;
                h2a[1][8] += hv.y * wc.x; h2a[1][9] += hv.y * wc.y;
            }
            // ---- PReLU2 + Wf dot -> per-(row, colg) partial logit
            #pragma unroll
            for (int rr = 0; rr < 2; ++rr) {
                const int lr = rowg * 2 + rr;
                const int t  = pass * 100 + lr;
                const float2* a2p = (const float2*)(a2 + t * 40 + colg * 10);
                float s = 0.f;
                #pragma unroll
                for (int u2 = 0; u2 < 5; ++u2) {
                    const float2 a = a2p[u2];
                    float x0 = h2a[rr][u2 * 2 + 0]; x0 = x0 > 0.f ? x0 : a.x * x0;
                    float x1 = h2a[rr][u2 * 2 + 1]; x1 = x1 > 0.f ? x1 : a.y * x1;
                    s += x0 * lds_wf[colg * 10 + u2 * 2 + 0]
                       + x1 * lds_wf[colg * 10 + u2 * 2 + 1];
                }
                lds_part[colg * 128 + lr] = s;
            }
        }
        __syncthreads();  // (e)
        if (tid < 100) {
            lds_logits[pass * 100 + tid] =
                lds_part[tid] + lds_part[128 + tid] +
                lds_part[256 + tid] + lds_part[384 + tid] + lds_bf;
        }
    }
    __syncthreads();

    // ---- softmax over 200 logits
    const float logit = (tid < 200) ? lds_logits[tid] : -INFINITY;
    lds_red[tid] = logit;
    __syncthreads();
    for (int off = 128; off > 0; off >>= 1) {
        if (tid < off) lds_red[tid] = fmaxf(lds_red[tid], lds_red[tid + off]);
        __syncthreads();
    }
    const float mx = lds_red[0];
    __syncthreads();
    const float ew = (tid < 200) ? __expf(logit - mx) : 0.0f;
    lds_red[tid] = ew;
    __syncthreads();
    for (int off = 128; off > 0; off >>= 1) {
        if (tid < off) lds_red[tid] += lds_red[tid + off];
        __syncthreads();
    }
    const float inv = 1.0f / lds_red[0];
    lds_w[tid] = ew * inv;
    __syncthreads();

    // ---- out[b][d] = sum_t w_t * v[b][t][d]
    const int g = tid >> 6, d = tid & 63;
    float accv = 0.0f;
    for (int tt = g; tt < T_; tt += 4)
        accv += lds_w[tt] * vb[tt * 64 + d];
    lds_acc[tid] = accv;
    __syncthreads();
    if (tid < 64)
        out[b * 64 + tid] = lds_acc[tid] + lds_acc[64 + tid]
                          + lds_acc[128 + tid] + lds_acc[192 + tid];
}

extern "C" void kernel_launch(void* const* d_in, const int* in_sizes, int n_in,
                              void* d_out, int out_size, void* d_ws, size_t ws_size,
                              hipStream_t stream) {
    const float* q  = (const float*)d_in[0];
    const float* k  = (const float*)d_in[1];
    const float* v  = (const float*)d_in[2];
    const float* W1 = (const float*)d_in[3];
    const float* b1 = (const float*)d_in[4];
    const float* a1 = (const float*)d_in[5];
    const float* W2 = (const float*)d_in[6];
    const float* b2 = (const float*)d_in[7];
    const float* a2 = (const float*)d_in[8];
    const float* Wf = (const float*)d_in[9];
    const float* bf = (const float*)d_in[10];
    float* out = (float*)d_out;

    hipLaunchKernelGGL(att_kernel, dim3(B_), dim3(256), 0, stream,
                       q, k, v, W1, b1, a1, W2, b2, a2, Wf, bf, out);
}

// Round 4
// 405.177 us; speedup vs baseline: 3.6406x; 1.1307x over previous
//
#include <hip/hip_runtime.h>
#include <math.h>

#define B_  2048
#define T_  200
#define D_  64
#define H1_ 80
#define H2_ 40

typedef short short8 __attribute__((ext_vector_type(8)));
typedef float f32x4  __attribute__((ext_vector_type(4)));

__device__ __forceinline__ unsigned short f2bf_rne(float x) {
    unsigned u = __float_as_uint(x);
    unsigned r = u + 0x7FFFu + ((u >> 16) & 1u);
    return (unsigned short)(r >> 16);
}
__device__ __forceinline__ float bf2f(unsigned short h) {
    return __uint_as_float(((unsigned)h) << 16);
}

// One block (256 thr = 4 waves) per batch element.
// Dense1 via split-bf16 MFMA 16x16x32 (hi*hi + hi*lo + lo*hi, ~2^-16 rel err).
//   A = k rows (m=t), B = wqT rows (n=j).  wq[kk][j] stored transposed.
//   Frag layouts (guide m89/m120 verified): A[m=lane&15][k=quad*8+j],
//   B[k=quad*8+j][n=lane&15], C/D col=lane&15 row=quad*4+reg.
// Dense2 on VALU with W2/b2/Wf on the SCALAR pipe (wave-uniform col block via
// readfirstlane) — only h1 comes from LDS (1 ds_read_b128 per 4 k-steps).
// 4 passes of 64 t-rows; 1 MFMA m-tile per wave per pass. LDS 69KB -> 2 blk/CU.
__global__ __launch_bounds__(256, 2)
void att_kernel(const float* __restrict__ q,
                const float* __restrict__ k,
                const float* __restrict__ v,
                const float* __restrict__ W1,
                const float* __restrict__ b1,
                const float* __restrict__ a1,
                const float* __restrict__ W2,
                const float* __restrict__ b2,
                const float* __restrict__ a2,
                const float* __restrict__ Wf,
                const float* __restrict__ bf,
                float* __restrict__ out)
{
    const int b    = blockIdx.x;
    const int tid  = threadIdx.x;
    const int lane = tid & 63;
    const int wv   = __builtin_amdgcn_readfirstlane(tid >> 6);  // wave id 0..3

    __shared__ unsigned short s_khi[64 * 72];   // k hi, row stride 72 (pad)
    __shared__ unsigned short s_klo[64 * 72];   // k lo
    __shared__ unsigned short s_wqhi[80 * 72];  // wq^T hi  [j][kk]
    __shared__ unsigned short s_wqlo[80 * 72];  // wq^T lo
    __shared__ float s_h1[64 * 84];             // h1 per pass, stride 84
    __shared__ float s_q[64];
    __shared__ float s_base1[80];
    __shared__ float s_part[256];
    __shared__ float s_logits[256];
    __shared__ float s_red[256];
    __shared__ float s_w[256];
    __shared__ float s_acc[256];

    const float* kb = k + (size_t)b * T_ * D_;
    const float* vb = v + (size_t)b * T_ * D_;

    if (tid < 64) s_q[tid] = q[b * 64 + tid];
    __syncthreads();

    // ---- phase 1: per-b weights.  wq[kk][j] = W1b - W1c + q[kk]*W1d, stored
    // transposed + split to bf16 hi/lo.  base1[j] = b1 + q@(W1a+W1c).
    for (int idx = tid; idx < 5120; idx += 256) {
        const int kk = idx / 80, j = idx - kk * 80;
        const float x = W1[5120 + idx] - W1[10240 + idx] + s_q[kk] * W1[15360 + idx];
        const unsigned short hi = f2bf_rne(x);
        s_wqhi[j * 72 + kk] = hi;
        s_wqlo[j * 72 + kk] = f2bf_rne(x - bf2f(hi));
    }
    if (tid < 80) {
        float s = b1[tid];
        for (int i = 0; i < 64; ++i)
            s += s_q[i] * (W1[i * 80 + tid] + W1[10240 + i * 80 + tid]);
        s_base1[tid] = s;
    }

    const float bfv  = bf[0];
    const int   mrow = wv * 16 + (lane & 15);   // A-frag row (local)
    const int   kq   = (lane >> 4) * 8;         // A/B-frag k offset
    const int   ncl  = lane & 15;

    for (int p = 0; p < 4; ++p) {
        __syncthreads();  // (a) k/h1 buffers free, prev logits reduced

        // ---- stage k rows [p*64, p*64+64) as split bf16
        {
            const int r  = tid >> 2;
            const int c0 = (tid & 3) * 16;
            const int t  = p * 64 + r;
            float xv[16];
            if (t < T_) {
                const float4* src = (const float4*)(kb + t * 64 + c0);
                #pragma unroll
                for (int i = 0; i < 4; ++i) {
                    const float4 f = src[i];
                    xv[i*4+0] = f.x; xv[i*4+1] = f.y; xv[i*4+2] = f.z; xv[i*4+3] = f.w;
                }
            } else {
                #pragma unroll
                for (int i = 0; i < 16; ++i) xv[i] = 0.f;
            }
            unsigned short hi[16], lo[16];
            #pragma unroll
            for (int i = 0; i < 16; ++i) {
                hi[i] = f2bf_rne(xv[i]);
                lo[i] = f2bf_rne(xv[i] - bf2f(hi[i]));
            }
            #pragma unroll
            for (int h = 0; h < 2; ++h) {
                short8 vh, vl;
                #pragma unroll
                for (int i = 0; i < 8; ++i) {
                    vh[i] = (short)hi[h * 8 + i];
                    vl[i] = (short)lo[h * 8 + i];
                }
                *(short8*)&s_khi[r * 72 + c0 + h * 8] = vh;
                *(short8*)&s_klo[r * 72 + c0 + h * 8] = vl;
            }
        }
        __syncthreads();  // (b) k staged

        // ---- Dense1 MFMA: wave wv owns m-tile wv (rows wv*16..+15 local)
        {
            const short8 ahi0 = *(short8*)&s_khi[mrow * 72 + kq];
            const short8 ahi1 = *(short8*)&s_khi[mrow * 72 + 32 + kq];
            const short8 alo0 = *(short8*)&s_klo[mrow * 72 + kq];
            const short8 alo1 = *(short8*)&s_klo[mrow * 72 + 32 + kq];
            #pragma unroll
            for (int nt = 0; nt < 5; ++nt) {
                const int n = nt * 16 + ncl;
                const short8 bhi0 = *(short8*)&s_wqhi[n * 72 + kq];
                const short8 bhi1 = *(short8*)&s_wqhi[n * 72 + 32 + kq];
                const short8 blo0 = *(short8*)&s_wqlo[n * 72 + kq];
                const short8 blo1 = *(short8*)&s_wqlo[n * 72 + 32 + kq];
                f32x4 acc = {0.f, 0.f, 0.f, 0.f};
                acc = __builtin_amdgcn_mfma_f32_16x16x32_bf16(ahi0, blo0, acc, 0, 0, 0);
                acc = __builtin_amdgcn_mfma_f32_16x16x32_bf16(alo0, bhi0, acc, 0, 0, 0);
                acc = __builtin_amdgcn_mfma_f32_16x16x32_bf16(ahi1, blo1, acc, 0, 0, 0);
                acc = __builtin_amdgcn_mfma_f32_16x16x32_bf16(alo1, bhi1, acc, 0, 0, 0);
                acc = __builtin_amdgcn_mfma_f32_16x16x32_bf16(ahi0, bhi0, acc, 0, 0, 0);
                acc = __builtin_amdgcn_mfma_f32_16x16x32_bf16(ahi1, bhi1, acc, 0, 0, 0);
                // epilogue: +base1, PReLU1, h1 -> LDS (C/D layout: col=ncl, row below)
                const float bbase = s_base1[n];
                #pragma unroll
                for (int r = 0; r < 4; ++r) {
                    const int tl = wv * 16 + (lane >> 4) * 4 + r;
                    int t = p * 64 + tl; if (t > T_ - 1) t = T_ - 1;  // clamp (values unused past T)
                    float x = acc[r] + bbase;
                    const float al = a1[t * 80 + n];
                    x = x > 0.f ? x : al * x;
                    s_h1[tl * 84 + n] = x;
                }
            }
        }
        __syncthreads();  // (c) h1 ready

        // ---- Dense2 on VALU: row = lane, cols wv*10..+9 (weights via s_load)
        {
            float h2[10];
            const float* b2c = b2 + wv * 10;
            #pragma unroll
            for (int u = 0; u < 10; ++u) h2[u] = b2c[u];
            for (int jc = 0; jc < 20; ++jc) {
                const float4 hv = *(const float4*)&s_h1[lane * 84 + jc * 4];
                const float* wr = W2 + (jc * 4) * 40 + wv * 10;   // uniform -> SGPR
                #pragma unroll
                for (int u = 0; u < 10; ++u) h2[u] += hv.x * wr[u];
                #pragma unroll
                for (int u = 0; u < 10; ++u) h2[u] += hv.y * wr[40 + u];
                #pragma unroll
                for (int u = 0; u < 10; ++u) h2[u] += hv.z * wr[80 + u];
                #pragma unroll
                for (int u = 0; u < 10; ++u) h2[u] += hv.w * wr[120 + u];
            }
            const int t = p * 64 + lane;
            if (t < T_) {
                const float* a2r = a2 + t * 40 + wv * 10;
                const float* wfr = Wf + wv * 10;                  // uniform -> SGPR
                float s = 0.f;
                #pragma unroll
                for (int u = 0; u < 10; ++u) {
                    float x = h2[u];
                    const float al = a2r[u];
                    x = x > 0.f ? x : al * x;
                    s += x * wfr[u];
                }
                s_part[wv * 64 + lane] = s;
            }
        }
        __syncthreads();  // (d) partials ready
        if (tid < 64) {
            const int t = p * 64 + tid;
            if (t < T_)
                s_logits[t] = s_part[tid] + s_part[64 + tid]
                            + s_part[128 + tid] + s_part[192 + tid] + bfv;
        }
    }
    __syncthreads();

    // ---- softmax over 200 logits
    const float logit = (tid < T_) ? s_logits[tid] : -INFINITY;
    s_red[tid] = logit;
    __syncthreads();
    for (int off = 128; off > 0; off >>= 1) {
        if (tid < off) s_red[tid] = fmaxf(s_red[tid], s_red[tid + off]);
        __syncthreads();
    }
    const float mx = s_red[0];
    __syncthreads();
    const float ew = (tid < T_) ? __expf(logit - mx) : 0.0f;
    s_red[tid] = ew;
    __syncthreads();
    for (int off = 128; off > 0; off >>= 1) {
        if (tid < off) s_red[tid] += s_red[tid + off];
        __syncthreads();
    }
    const float inv = 1.0f / s_red[0];
    s_w[tid] = ew * inv;
    __syncthreads();

    // ---- out[b][d] = sum_t w_t * v[b][t][d]
    const int g = tid >> 6, d = tid & 63;
    float accv = 0.0f;
    for (int tt = g; tt < T_; tt += 4)
        accv += s_w[tt] * vb[tt * 64 + d];
    s_acc[tid] = accv;
    __syncthreads();
    if (tid < 64)
        out[b * 64 + tid] = s_acc[tid] + s_acc[64 + tid]
                          + s_acc[128 + tid] + s_acc[192 + tid];
}

extern "C" void kernel_launch(void* const* d_in, const int* in_sizes, int n_in,
                              void* d_out, int out_size, void* d_ws, size_t ws_size,
                              hipStream_t stream) {
    const float* q  = (const float*)d_in[0];
    const float* k  = (const float*)d_in[1];
    const float* v  = (const float*)d_in[2];
    const float* W1 = (const float*)d_in[3];
    const float* b1 = (const float*)d_in[4];
    const float* a1 = (const float*)d_in[5];
    const float* W2 = (const float*)d_in[6];
    const float* b2 = (const float*)d_in[7];
    const float* a2 = (const float*)d_in[8];
    const float* Wf = (const float*)d_in[9];
    const float* bf = (const float*)d_in[10];
    float* out = (float*)d_out;

    hipLaunchKernelGGL(att_kernel, dim3(B_), dim3(256), 0, stream,
                       q, k, v, W1, b1, a1, W2, b2, a2, Wf, bf, out);
}

// Round 5
// 342.841 us; speedup vs baseline: 4.3026x; 1.1818x over previous
//
#include <hip/hip_runtime.h>
#include <math.h>

#define B_  2048
#define T_  200

typedef short short8 __attribute__((ext_vector_type(8)));
typedef float f32x4  __attribute__((ext_vector_type(4)));

__device__ __forceinline__ unsigned short f2bf_rne(float x) {
    unsigned u = __float_as_uint(x);
    unsigned r = u + 0x7FFFu + ((u >> 16) & 1u);
    return (unsigned short)(r >> 16);
}
__device__ __forceinline__ float bf2f(unsigned short h) {
    return __uint_as_float(((unsigned)h) << 16);
}
__device__ __forceinline__ void split2(float x, unsigned short& hi, unsigned short& lo) {
    hi = f2bf_rne(x); lo = f2bf_rne(x - bf2f(hi));
}

// One block (4 waves) per batch element b. The 13-m-tile loop is BARRIER-FREE:
// every LDS dependency (h1 round-trip) is wave-local (rows wv*16..wv*16+15),
// k comes straight from global into A-fragments, W2 fragments live in VGPRs.
// Dense1: h1pre = k @ wq + base1 (split-bf16 MFMA, K=64)
// Dense2: h2 = PReLU1(h1) @ W2 (split-bf16 MFMA, K=80 pad 96, n=40 pad 48)
// logit = PReLU2(h2)@Wf + bf folded into the MFMA epilogue + butterfly.
__global__ __launch_bounds__(256, 3)
void att_kernel(const float* __restrict__ q,
                const float* __restrict__ k,
                const float* __restrict__ v,
                const float* __restrict__ W1,
                const float* __restrict__ b1,
                const float* __restrict__ a1,
                const float* __restrict__ W2,
                const float* __restrict__ b2,
                const float* __restrict__ a2,
                const float* __restrict__ Wf,
                const float* __restrict__ bf,
                float* __restrict__ out)
{
    const int b    = blockIdx.x;
    const int tid  = threadIdx.x;
    const int lane = tid & 63;
    const int wv   = __builtin_amdgcn_readfirstlane(tid >> 6);
    const int ncl  = lane & 15;
    const int q4   = lane >> 4;
    const int kq   = q4 * 8;

    __shared__ unsigned short s_wqhi[80 * 72];               // 11.5 KB
    __shared__ unsigned short s_wqlo[80 * 72];               // 11.5 KB
    __shared__ __align__(16) unsigned short s_h1[2 * 64 * 104]; // 26 KB, unioned
    __shared__ float s_q[64];
    __shared__ float s_base1[80];
    __shared__ float s_logits[256];

    unsigned short* s_h1hi = s_h1;
    unsigned short* s_h1lo = s_h1 + 64 * 104;
    // softmax/v-sum scratch aliases s_h1 (dead after the tile loop):
    float*  u_w   = (float*)s_h1;                 // [256]  bytes 0..1023
    float4* u_acc = (float4*)(s_h1 + 512);        // [256]  bytes 1024..5119
    float*  u_red = (float*)(s_h1 + 2560);        // [8]    bytes 5120..5151

    const float* kb = k + (size_t)b * T_ * 64;
    const float* vb = v + (size_t)b * T_ * 64;

    if (tid < 64) s_q[tid] = q[b * 64 + tid];
    __syncthreads();

    // ---- prologue: per-b wq (split bf16, B-layout [j][kk]), base1, h1 k-pad
    for (int idx = tid; idx < 5120; idx += 256) {
        const int kk = idx / 80, j = idx - kk * 80;
        const float x = W1[5120 + idx] - W1[10240 + idx] + s_q[kk] * W1[15360 + idx];
        unsigned short hi, lo; split2(x, hi, lo);
        s_wqhi[j * 72 + kk] = hi;
        s_wqlo[j * 72 + kk] = lo;
    }
    if (tid < 80) {
        float s0 = b1[tid], s1 = 0.f;
        #pragma unroll 4
        for (int i = 0; i < 64; i += 2) {
            s0 += s_q[i]     * (W1[i * 80 + tid]       + W1[10240 + i * 80 + tid]);
            s1 += s_q[i + 1] * (W1[(i + 1) * 80 + tid] + W1[10240 + (i + 1) * 80 + tid]);
        }
        s_base1[tid] = s0 + s1;
    }
    for (int idx = tid; idx < 1024; idx += 256) {   // zero h1 cols 80..95 (K-pad)
        const int r = idx >> 4, c = 80 + (idx & 15);
        s_h1hi[r * 104 + c] = 0;
        s_h1lo[r * 104 + c] = 0;
    }
    __syncthreads();

    // ---- hoist W2 B-fragments into registers (built from L2, once per block)
    short8 w2h[3][3], w2l[3][3];
    #pragma unroll
    for (int nt = 0; nt < 3; ++nt) {
        const int n = nt * 16 + ncl;
        #pragma unroll
        for (int c = 0; c < 3; ++c) {
            short8 hh, ll;
            #pragma unroll
            for (int jj = 0; jj < 8; ++jj) {
                const int kk = c * 32 + kq + jj;
                const float x = (kk < 80 && n < 40) ? W2[kk * 40 + n] : 0.f;
                unsigned short hi, lo; split2(x, hi, lo);
                hh[jj] = (short)hi; ll[jj] = (short)lo;
            }
            w2h[nt][c] = hh; w2l[nt][c] = ll;
        }
    }
    float wf3[3], b23[3], bb1[5];
    #pragma unroll
    for (int nt = 0; nt < 3; ++nt) {
        const int n = nt * 16 + ncl;
        wf3[nt] = (n < 40) ? Wf[n] : 0.f;
        b23[nt] = (n < 40) ? b2[n] : 0.f;
    }
    #pragma unroll
    for (int nt = 0; nt < 5; ++nt) bb1[nt] = s_base1[nt * 16 + ncl];
    const float bfv = bf[0];

    // ---- barrier-free tile loop: wave wv owns m-tiles wv, wv+4, wv+8, wv+12
    const int h1row = (wv * 16 + ncl) * 104;
    for (int mt = wv; mt < 13; mt += 4) {
        // A-fragments (k) straight from global, split bf16
        const int trow = mt * 16 + ncl;
        float4 ka0 = {0,0,0,0}, ka1 = ka0, ka2 = ka0, ka3 = ka0;
        if (trow < T_) {
            const float4* kr = (const float4*)(kb + trow * 64);
            ka0 = kr[q4 * 2];     ka1 = kr[q4 * 2 + 1];
            ka2 = kr[8 + q4 * 2]; ka3 = kr[8 + q4 * 2 + 1];
        }
        const float a0v[8] = {ka0.x, ka0.y, ka0.z, ka0.w, ka1.x, ka1.y, ka1.z, ka1.w};
        const float a1v[8] = {ka2.x, ka2.y, ka2.z, ka2.w, ka3.x, ka3.y, ka3.z, ka3.w};
        short8 ahi0, alo0, ahi1, alo1;
        #pragma unroll
        for (int jj = 0; jj < 8; ++jj) {
            unsigned short h, l;
            split2(a0v[jj], h, l); ahi0[jj] = (short)h; alo0[jj] = (short)l;
            split2(a1v[jj], h, l); ahi1[jj] = (short)h; alo1[jj] = (short)l;
        }

        // Dense1 MFMA + PReLU1 epilogue -> h1 (wave-local LDS round-trip)
        #pragma unroll
        for (int nt = 0; nt < 5; ++nt) {
            const int n = nt * 16 + ncl;
            const short8 bhi0 = *(const short8*)&s_wqhi[n * 72 + kq];
            const short8 bhi1 = *(const short8*)&s_wqhi[n * 72 + 32 + kq];
            const short8 blo0 = *(const short8*)&s_wqlo[n * 72 + kq];
            const short8 blo1 = *(const short8*)&s_wqlo[n * 72 + 32 + kq];
            f32x4 acc = {0.f, 0.f, 0.f, 0.f};
            acc = __builtin_amdgcn_mfma_f32_16x16x32_bf16(ahi0, blo0, acc, 0, 0, 0);
            acc = __builtin_amdgcn_mfma_f32_16x16x32_bf16(alo0, bhi0, acc, 0, 0, 0);
            acc = __builtin_amdgcn_mfma_f32_16x16x32_bf16(ahi1, blo1, acc, 0, 0, 0);
            acc = __builtin_amdgcn_mfma_f32_16x16x32_bf16(alo1, bhi1, acc, 0, 0, 0);
            acc = __builtin_amdgcn_mfma_f32_16x16x32_bf16(ahi0, bhi0, acc, 0, 0, 0);
            acc = __builtin_amdgcn_mfma_f32_16x16x32_bf16(ahi1, bhi1, acc, 0, 0, 0);
            #pragma unroll
            for (int r = 0; r < 4; ++r) {
                const int rloc = q4 * 4 + r;
                int t = mt * 16 + rloc; if (t > T_ - 1) t = T_ - 1;
                float x = acc[r] + bb1[nt];
                const float al = a1[t * 80 + n];
                x = x > 0.f ? x : al * x;
                unsigned short hi, lo; split2(x, hi, lo);
                s_h1hi[(wv * 16 + rloc) * 104 + n] = hi;
                s_h1lo[(wv * 16 + rloc) * 104 + n] = lo;
            }
        }

        // Dense2 MFMA (W2 frags in regs) + PReLU2*Wf epilogue -> logits
        short8 ah[3], al[3];
        #pragma unroll
        for (int c = 0; c < 3; ++c) {
            ah[c] = *(const short8*)&s_h1hi[h1row + c * 32 + kq];
            al[c] = *(const short8*)&s_h1lo[h1row + c * 32 + kq];
        }
        float part[4] = {0.f, 0.f, 0.f, 0.f};
        #pragma unroll
        for (int nt = 0; nt < 3; ++nt) {
            f32x4 acc = {0.f, 0.f, 0.f, 0.f};
            #pragma unroll
            for (int c = 0; c < 3; ++c) {
                acc = __builtin_amdgcn_mfma_f32_16x16x32_bf16(ah[c], w2l[nt][c], acc, 0, 0, 0);
                acc = __builtin_amdgcn_mfma_f32_16x16x32_bf16(al[c], w2h[nt][c], acc, 0, 0, 0);
                acc = __builtin_amdgcn_mfma_f32_16x16x32_bf16(ah[c], w2h[nt][c], acc, 0, 0, 0);
            }
            const int n = nt * 16 + ncl;
            #pragma unroll
            for (int r = 0; r < 4; ++r) {
                int t = mt * 16 + q4 * 4 + r; if (t > T_ - 1) t = T_ - 1;
                float x = acc[r] + b23[nt];
                const float al2 = (n < 40) ? a2[t * 40 + n] : 0.f;
                x = x > 0.f ? x : al2 * x;
                part[r] += x * wf3[nt];
            }
        }
        #pragma unroll
        for (int r = 0; r < 4; ++r) {
            float p = part[r];
            p += __shfl_xor(p, 1, 64);
            p += __shfl_xor(p, 2, 64);
            p += __shfl_xor(p, 4, 64);
            p += __shfl_xor(p, 8, 64);
            part[r] = p;
        }
        if (ncl == 0) {
            #pragma unroll
            for (int r = 0; r < 4; ++r) {
                const int t = mt * 16 + q4 * 4 + r;
                if (t < T_) s_logits[t] = part[r] + bfv;
            }
        }
    }
    __syncthreads();   // logits complete; s_h1 dead -> scratch reuse OK

    // ---- softmax over 200 logits (wave shuffles, 2 barriers)
    float logit = -INFINITY;
    if (tid < T_) logit = s_logits[tid];
    float mred = logit;
    #pragma unroll
    for (int off = 1; off < 64; off <<= 1) mred = fmaxf(mred, __shfl_xor(mred, off, 64));
    if (lane == 0) u_red[wv] = mred;
    __syncthreads();
    const float mx = fmaxf(fmaxf(u_red[0], u_red[1]), fmaxf(u_red[2], u_red[3]));
    const float ew = (tid < T_) ? __expf(logit - mx) : 0.f;
    float ssum = ew;
    #pragma unroll
    for (int off = 1; off < 64; off <<= 1) ssum += __shfl_xor(ssum, off, 64);
    if (lane == 0) u_red[4 + wv] = ssum;
    __syncthreads();
    const float tot = (u_red[4] + u_red[5]) + (u_red[6] + u_red[7]);
    const float inv = 1.0f / tot;
    u_w[tid] = ew * inv;
    __syncthreads();

    // ---- out[b][d] = sum_t w_t * v[b][t][d]  (float4 lanes, 16 t-groups)
    const int c4 = tid & 15, g = tid >> 4;
    float4 acc4 = {0.f, 0.f, 0.f, 0.f};
    const float4* vb4 = (const float4*)vb;
    for (int t = g; t < T_; t += 16) {
        const float wt = u_w[t];
        const float4 vv = vb4[t * 16 + c4];
        acc4.x += wt * vv.x; acc4.y += wt * vv.y;
        acc4.z += wt * vv.z; acc4.w += wt * vv.w;
    }
    u_acc[tid] = acc4;
    __syncthreads();
    if (tid < 64) {
        const float* uf = (const float*)u_acc;
        float s = 0.f;
        #pragma unroll
        for (int gg = 0; gg < 16; ++gg) s += uf[gg * 64 + tid];
        out[b * 64 + tid] = s;
    }
}

extern "C" void kernel_launch(void* const* d_in, const int* in_sizes, int n_in,
                              void* d_out, int out_size, void* d_ws, size_t ws_size,
                              hipStream_t stream) {
    const float* q  = (const float*)d_in[0];
    const float* k  = (const float*)d_in[1];
    const float* v  = (const float*)d_in[2];
    const float* W1 = (const float*)d_in[3];
    const float* b1 = (const float*)d_in[4];
    const float* a1 = (const float*)d_in[5];
    const float* W2 = (const float*)d_in[6];
    const float* b2 = (const float*)d_in[7];
    const float* a2 = (const float*)d_in[8];
    const float* Wf = (const float*)d_in[9];
    const float* bf = (const float*)d_in[10];
    float* out = (float*)d_out;

    hipLaunchKernelGGL(att_kernel, dim3(B_), dim3(256), 0, stream,
                       q, k, v, W1, b1, a1, W2, b2, a2, Wf, bf, out);
}